// Round 3
// baseline (358.997 us; speedup 1.0000x reference)
//
#include <hip/hip_runtime.h>

// ---------------------------------------------------------------------------
// BoTNet attention head on MI355X (gfx950).
// conv1x1+BN+ReLU -> qkv conv -> rel-logit MFMA precompute ->
// flash attention (bf16 MFMA, 32q/wave, split-K=4, defer-max, async K/V) ->
// merge -> conv1x1(MFMA)+BN+residual+ReLU -> conv1x1(MFMA) head.
// ---------------------------------------------------------------------------

typedef __attribute__((ext_vector_type(4))) float f32x4;
typedef __attribute__((ext_vector_type(8))) short s16x8;
typedef __attribute__((ext_vector_type(4))) unsigned short u16x4;

#define HW_N 4608
#define EPS 1e-5f
#define QSCALE 0.08838834764831845f  // 128^-0.5

__device__ __forceinline__ unsigned short f2bf(float f) {
  unsigned u = __builtin_bit_cast(unsigned, f);
  u += 0x7fffu + ((u >> 16) & 1u);          // round-to-nearest-even
  return (unsigned short)(u >> 16);
}
__device__ __forceinline__ float bf2f(unsigned short s) {
  return __builtin_bit_cast(float, ((unsigned)s) << 16);
}
__device__ __forceinline__ void gload_lds16(const void* g, void* l) {
  __builtin_amdgcn_global_load_lds(g, l, 16, 0, 0);
}

// ---------------------------------------------------------------------------
// conv1: h1[64][4608] = relu(bn(w_in @ x)); K=256  (fp32, unchanged)
// ---------------------------------------------------------------------------
__global__ __launch_bounds__(256) void conv1_kernel(
    const float* __restrict__ x, const float* __restrict__ w,
    const float* __restrict__ gg, const float* __restrict__ bb,
    const float* __restrict__ mm, const float* __restrict__ vv,
    float* __restrict__ h1)
{
  __shared__ __align__(16) unsigned char smA[16384];
  __shared__ __align__(16) unsigned char smB[16384];
  const int tid = (int)threadIdx.x;
  const int tx = tid & 15, ty = tid >> 4;
  const int p0 = (int)blockIdx.x * 64;
  float acc[4][4] = {};
  for (int ch = 0; ch < 4; ++ch) {
    __syncthreads();
#pragma unroll
    for (int pass = 0; pass < 4; ++pass) {
      int c4 = tid + pass * 256;
      int oc = c4 >> 4, cc4 = c4 & 15;
      f32x4 a = *(const f32x4*)(w + oc * 256 + ch * 64 + cc4 * 4);
#pragma unroll
      for (int k = 0; k < 4; ++k) {
        int cc = cc4 * 4 + k;
        *(float*)(smA + cc * 256 + ((oc * 4) ^ ((cc & 7) << 4))) = a[k];
      }
      int cc = c4 >> 4, pp4 = c4 & 15;
      f32x4 b = *(const f32x4*)(x + (ch * 64 + cc) * HW_N + p0 + pp4 * 4);
      *(f32x4*)(smB + cc * 256 + ((pp4 * 16) ^ ((cc & 7) << 4))) = b;
    }
    __syncthreads();
#pragma unroll 8
    for (int cc = 0; cc < 64; ++cc) {
      f32x4 av = *(const f32x4*)(smA + cc * 256 + ((ty * 16) ^ ((cc & 7) << 4)));
      f32x4 bv = *(const f32x4*)(smB + cc * 256 + ((tx * 16) ^ ((cc & 7) << 4)));
#pragma unroll
      for (int i = 0; i < 4; ++i)
#pragma unroll
        for (int j = 0; j < 4; ++j) acc[i][j] = fmaf(av[i], bv[j], acc[i][j]);
    }
  }
#pragma unroll
  for (int i = 0; i < 4; ++i) {
    int oc = ty * 4 + i;
    float inv = gg[oc] * rsqrtf(vv[oc] + EPS);
    float bia = bb[oc] - mm[oc] * inv;
    f32x4 o;
#pragma unroll
    for (int j = 0; j < 4; ++j) o[j] = fmaxf(acc[i][j] * inv + bia, 0.f);
    *(f32x4*)(h1 + oc * HW_N + p0 + tx * 4) = o;
  }
}

// ---------------------------------------------------------------------------
// convqkv (fp32, unchanged): qkv = w_qkv @ h1; scatter q(scaled)/k [h][p][128],
// v [h][128][p] bf16.
// ---------------------------------------------------------------------------
__global__ __launch_bounds__(256) void convqkv_kernel(
    const float* __restrict__ h1, const float* __restrict__ w,
    unsigned short* __restrict__ qb, unsigned short* __restrict__ kb,
    unsigned short* __restrict__ vb)
{
  __shared__ __align__(16) unsigned char smA[16384];
  __shared__ __align__(16) unsigned char smB[16384];
  const int tid = (int)threadIdx.x;
  const int tx = tid & 15, ty = tid >> 4;
  const int p0 = (int)blockIdx.x * 64;
  const int o0 = (int)blockIdx.y * 64;
  float acc[4][4] = {};
#pragma unroll
  for (int pass = 0; pass < 4; ++pass) {
    int c4 = tid + pass * 256;
    int oc = c4 >> 4, cc4 = c4 & 15;
    f32x4 a = *(const f32x4*)(w + (o0 + oc) * 64 + cc4 * 4);
#pragma unroll
    for (int k = 0; k < 4; ++k) {
      int cc = cc4 * 4 + k;
      *(float*)(smA + cc * 256 + ((oc * 4) ^ ((cc & 7) << 4))) = a[k];
    }
    int cc = c4 >> 4, pp4 = c4 & 15;
    f32x4 b = *(const f32x4*)(h1 + cc * HW_N + p0 + pp4 * 4);
    *(f32x4*)(smB + cc * 256 + ((pp4 * 16) ^ ((cc & 7) << 4))) = b;
  }
  __syncthreads();
#pragma unroll 8
  for (int cc = 0; cc < 64; ++cc) {
    f32x4 av = *(const f32x4*)(smA + cc * 256 + ((tx * 16) ^ ((cc & 7) << 4)));
    f32x4 bv = *(const f32x4*)(smB + cc * 256 + ((ty * 16) ^ ((cc & 7) << 4)));
#pragma unroll
    for (int i = 0; i < 4; ++i)
#pragma unroll
      for (int j = 0; j < 4; ++j) acc[i][j] = fmaf(av[i], bv[j], acc[i][j]);
  }
  const int chunk = o0 >> 9, head = (o0 >> 7) & 3, dbase = o0 & 127;
  if (chunk == 0) {
#pragma unroll
    for (int j = 0; j < 4; ++j) {
      unsigned short pk[4];
#pragma unroll
      for (int i = 0; i < 4; ++i) pk[i] = f2bf(acc[i][j] * QSCALE);
      *(unsigned long long*)(qb + (head * HW_N + p0 + ty * 4 + j) * 128 + dbase + tx * 4) =
          *(unsigned long long*)pk;
    }
  } else if (chunk == 1) {
#pragma unroll
    for (int j = 0; j < 4; ++j) {
      unsigned short pk[4];
#pragma unroll
      for (int i = 0; i < 4; ++i) pk[i] = f2bf(acc[i][j]);
      *(unsigned long long*)(kb + (head * HW_N + p0 + ty * 4 + j) * 128 + dbase + tx * 4) =
          *(unsigned long long*)pk;
    }
  } else {
#pragma unroll
    for (int i = 0; i < 4; ++i) {
      unsigned short pk[4];
#pragma unroll
      for (int j = 0; j < 4; ++j) pk[j] = f2bf(acc[i][j]);
      *(unsigned long long*)(vb + (head * 128 + dbase + tx * 4 + i) * HW_N + p0 + ty * 4) =
          *(unsigned long long*)pk;
    }
  }
}

// ---------------------------------------------------------------------------
// relpre via MFMA (combined): bx<96 -> mode0 (wq=bx): C[48 hq][96 wk] vs rel_w
//                             bx>=96 -> mode1 (hq=bx-96): C[96 wq][48 hk] vs rel_h
// ---------------------------------------------------------------------------
__global__ __launch_bounds__(256) void relpre_mfma(
    const unsigned short* __restrict__ qb,
    const float* __restrict__ rel_h, const float* __restrict__ rel_w,
    float* __restrict__ RW, float* __restrict__ RH)
{
  __shared__ __align__(16) unsigned char sm[36864];
  int bxr = (int)blockIdx.x;
  const int mode = bxr >= 96;
  const int bx = mode ? bxr - 96 : bxr;
  const int h = (int)blockIdx.y;
  const int tid = (int)threadIdx.x;
  const int wv = tid >> 6, g = (tid >> 4) & 3, c = tid & 15;
  const int NA = mode ? 96 : 48;
  const int NB = mode ? 48 : 96;
  const int TC = NB >> 4;
  const int roff = mode ? (47 - bx) : (95 - bx);
  const float* rel = mode ? rel_h : rel_w;
  float* outp = mode ? RH : RW;
  unsigned char* const smQ = sm;
  unsigned char* const smR = sm + NA * 256;

  for (int ch = tid; ch < (NA + NB) * 16; ch += 256) {
    if (ch < NA * 16) {
      int i = ch >> 4, d8 = ch & 15;
      int p = mode ? (bx * 96 + i) : (i * 96 + bx);
      s16x8 v = *(const s16x8*)(qb + ((size_t)h * HW_N + p) * 128 + d8 * 8);
      *(s16x8*)(smQ + i * 256 + ((d8 * 16) ^ ((i & 7) << 4))) = v;
    } else {
      int c2 = ch - NA * 16;
      int j = c2 >> 4, d8 = c2 & 15;
      const float* rp = rel + (roff + j) * 128 + d8 * 8;
      f32x4 r0 = *(const f32x4*)(rp);
      f32x4 r1 = *(const f32x4*)(rp + 4);
      s16x8 pk;
#pragma unroll
      for (int e = 0; e < 4; ++e) {
        pk[e] = (short)f2bf(r0[e]);
        pk[4 + e] = (short)f2bf(r1[e]);
      }
      *(s16x8*)(smR + j * 256 + ((d8 * 16) ^ ((j & 7) << 4))) = pk;
    }
  }
  __syncthreads();

  const int swzc = (c & 7) << 4;
  for (int tile = wv; tile < 18; tile += 4) {
    const int tr = tile / TC, tc = tile % TC;
    f32x4 acc = {};
#pragma unroll
    for (int kk = 0; kk < 4; ++kk) {
      const int koff = (kk * 64 + g * 16) ^ swzc;
      s16x8 a = *(const s16x8*)(smQ + (tr * 16 + c) * 256 + koff);
      s16x8 b = *(const s16x8*)(smR + (tc * 16 + c) * 256 + koff);
      acc = __builtin_amdgcn_mfma_f32_16x16x32_bf16(a, b, acc, 0, 0, 0);
    }
#pragma unroll
    for (int j = 0; j < 4; ++j) {
      int i = tr * 16 + g * 4 + j;
      int n = tc * 16 + c;
      if (mode == 0)
        outp[((size_t)h * HW_N + i * 96 + bx) * 96 + n] = acc[j];
      else
        outp[((size_t)h * HW_N + bx * 96 + i) * 48 + n] = acc[j];
    }
  }
}

// ---------------------------------------------------------------------------
// flash attention v3. grid (36,4,4): 16 (h,kh) groups x 36 q-tiles (128 q).
// block 256 = 4 waves x 32 queries. 48-key tiles (image half-rows).
// smK double-buffered via global_load_lds (pre-swizzled src); V reg-staged
// with post-barrier prefetch. Split-K=4, defer-max THR=8, bf16 Opart.
// ---------------------------------------------------------------------------
__global__ __launch_bounds__(256, 2) void attn_kernel(
    const unsigned short* __restrict__ qb,
    const unsigned short* __restrict__ kbuf,
    const unsigned short* __restrict__ vbuf,
    const float* __restrict__ RW,
    const float* __restrict__ RH,
    unsigned short* __restrict__ Opart,
    float* __restrict__ mlbuf)
{
  __shared__ __align__(16) unsigned char sm[57344];
  unsigned char* const smK = sm;          // 2 x [48 keys][128 d] bf16, swz (row&7)<<4
  unsigned char* const smV = sm + 24576;  // [128 d][64 slots] bf16, swz (d&7)<<4
  unsigned char* const smP = sm + 40960;  // [128 q][64 slots] bf16, swz (q&7)<<4

  const int tid = (int)threadIdx.x;
  const int wv = tid >> 6;
  const int g = (tid >> 4) & 3;
  const int c = tid & 15;
  const int swzc = (c & 7) << 4;

  int lin = (int)blockIdx.x + 36 * ((int)blockIdx.y + 4 * (int)blockIdx.z);
  const int grp = lin & 15, qt = lin >> 4;
  const int h = grp & 3, kh = grp >> 2;

  const int qbaseW = qt * 128 + wv * 32;
  const int pb = (kh * 4 + h) * HW_N;

  {  // zero smP (16KB) and smV pad slots
    s16x8 z = {};
#pragma unroll
    for (int i = 0; i < 4; ++i) *(s16x8*)(smP + i * 4096 + tid * 16) = z;
    int d = tid >> 1, k6 = 6 + (tid & 1);
    *(s16x8*)(smV + d * 128 + ((k6 * 16) ^ ((d & 7) << 4))) = z;
  }

  // Q fragments
  s16x8 aq[2][4];
#pragma unroll
  for (int u = 0; u < 2; ++u) {
    const unsigned short* qrow = qb + ((size_t)h * HW_N + qbaseW + u * 16 + c) * 128 + g * 8;
#pragma unroll
    for (int kk = 0; kk < 4; ++kk) aq[u][kk] = *(const s16x8*)(qrow + kk * 32);
  }

  // bias registers
  float bw0[3][2][4], bw1[3][2][4];   // [kb][u][r]
  float rh_pre[2][4];
#pragma unroll
  for (int u = 0; u < 2; ++u)
#pragma unroll
    for (int r = 0; r < 4; ++r) {
      const int q = qbaseW + u * 16 + g * 4 + r;
      const float* rwrow = RW + ((size_t)h * HW_N + q) * 96 + c;
#pragma unroll
      for (int kb = 0; kb < 3; ++kb) {
        bw0[kb][u][r] = rwrow[kb * 16];
        bw1[kb][u][r] = rwrow[48 + kb * 16];
      }
      rh_pre[u][r] = (c < 12) ? RH[((size_t)h * HW_N + q) * 48 + kh * 12 + c] : 0.f;
    }

  f32x4 o[2][8];
#pragma unroll
  for (int u = 0; u < 2; ++u)
#pragma unroll
    for (int cb = 0; cb < 8; ++cb) o[u][cb] = {};
  float mrun[2][4], lrun[2][4];
#pragma unroll
  for (int u = 0; u < 2; ++u)
#pragma unroll
    for (int r = 0; r < 4; ++r) { mrun[u][r] = -1e30f; lrun[u][r] = 0.f; }

  const char* kbase = (const char*)kbuf + ((size_t)h * HW_N + kh * 1152) * 256;
  const unsigned short* vbase = vbuf + (size_t)h * 128 * HW_N + kh * 1152;

  // staging constants
  const int krow4 = tid >> 4, kd8 = tid & 15;
  const int ksrcoff = (kd8 * 16) ^ ((krow4 & 7) << 4);
  const int vd0 = tid / 6, vk0 = tid % 6;
  const int vd1 = (tid + 256) / 6, vk1 = (tid + 256) % 6;
  const int vd2 = (tid + 512) / 6, vk2 = (tid + 512) % 6;

  s16x8 sV0, sV1, sV2;
  {  // prologue: async K tile0 -> buf0; V regs tile0
#pragma unroll
    for (int i = 0; i < 3; ++i)
      gload_lds16(kbase + (size_t)(i * 16 + krow4) * 256 + ksrcoff,
                  smK + i * 4096 + wv * 1024);
    sV0 = *(const s16x8*)(vbase + vd0 * HW_N + vk0 * 8);
    sV1 = *(const s16x8*)(vbase + vd1 * HW_N + vk1 * 8);
    sV2 = *(const s16x8*)(vbase + vd2 * HW_N + vk2 * 8);
  }

  for (int t = 0; t < 24; ++t) {
    __syncthreads();  // drains async K(t) + V-reg loads(t); prev reads done
    *(s16x8*)(smV + vd0 * 128 + ((vk0 * 16) ^ ((vd0 & 7) << 4))) = sV0;
    *(s16x8*)(smV + vd1 * 128 + ((vk1 * 16) ^ ((vd1 & 7) << 4))) = sV1;
    *(s16x8*)(smV + vd2 * 128 + ((vk2 * 16) ^ ((vd2 & 7) << 4))) = sV2;
    float rh_[2][4];
#pragma unroll
    for (int u = 0; u < 2; ++u)
#pragma unroll
      for (int r = 0; r < 4; ++r) rh_[u][r] = __shfl(rh_pre[u][r], t >> 1, 16);
    __syncthreads();  // smV/smK(t) visible
    const unsigned char* smKb = smK + (t & 1) * 12288;
    if (t < 23) {  // prefetch t+1 during compute
      const int nb = (t + 1) & 1;
#pragma unroll
      for (int i = 0; i < 3; ++i)
        gload_lds16(kbase + (size_t)((t + 1) * 48 + i * 16 + krow4) * 256 + ksrcoff,
                    smK + nb * 12288 + i * 4096 + wv * 1024);
      const int j0n = (t + 1) * 48;
      sV0 = *(const s16x8*)(vbase + vd0 * HW_N + j0n + vk0 * 8);
      sV1 = *(const s16x8*)(vbase + vd1 * HW_N + j0n + vk1 * 8);
      sV2 = *(const s16x8*)(vbase + vd2 * HW_N + j0n + vk2 * 8);
    }

    // ---- S = Q K^T (32q x 48k per wave) ----
    f32x4 s[2][3];
#pragma unroll
    for (int u = 0; u < 2; ++u)
#pragma unroll
      for (int kb = 0; kb < 3; ++kb) s[u][kb] = {};
#pragma unroll
    for (int kk = 0; kk < 4; ++kk) {
      const int inr = (kk * 64 + g * 16) ^ swzc;
      s16x8 b0 = *(const s16x8*)(smKb + c * 256 + inr);
      s16x8 b1 = *(const s16x8*)(smKb + (16 + c) * 256 + inr);
      s16x8 b2 = *(const s16x8*)(smKb + (32 + c) * 256 + inr);
#pragma unroll
      for (int u = 0; u < 2; ++u) {
        s[u][0] = __builtin_amdgcn_mfma_f32_16x16x32_bf16(aq[u][kk], b0, s[u][0], 0, 0, 0);
        s[u][1] = __builtin_amdgcn_mfma_f32_16x16x32_bf16(aq[u][kk], b1, s[u][1], 0, 0, 0);
        s[u][2] = __builtin_amdgcn_mfma_f32_16x16x32_bf16(aq[u][kk], b2, s[u][2], 0, 0, 0);
      }
    }

    // ---- bias + online softmax (defer-max THR=8) ----
    const bool par = (t & 1) != 0;
    float tm3[2][4];
    int need = 0;
#pragma unroll
    for (int u = 0; u < 2; ++u)
#pragma unroll
      for (int r = 0; r < 4; ++r) {
        float x0 = s[u][0][r] + (par ? bw1[0][u][r] : bw0[0][u][r]) + rh_[u][r];
        float x1 = s[u][1][r] + (par ? bw1[1][u][r] : bw0[1][u][r]) + rh_[u][r];
        float x2 = s[u][2][r] + (par ? bw1[2][u][r] : bw0[2][u][r]) + rh_[u][r];
        s[u][0][r] = x0; s[u][1][r] = x1; s[u][2][r] = x2;
        tm3[u][r] = fmaxf(fmaxf(x0, x1), x2);
        need |= (tm3[u][r] > mrun[u][r] + 8.f);
      }
    if (__any(need)) {
#pragma unroll
      for (int u = 0; u < 2; ++u)
#pragma unroll
        for (int r = 0; r < 4; ++r) {
          float tg = tm3[u][r];
          tg = fmaxf(tg, __shfl_xor(tg, 1, 16));
          tg = fmaxf(tg, __shfl_xor(tg, 2, 16));
          tg = fmaxf(tg, __shfl_xor(tg, 4, 16));
          tg = fmaxf(tg, __shfl_xor(tg, 8, 16));
          float mn = fmaxf(mrun[u][r], tg);
          float fac = __expf(mrun[u][r] - mn);
          mrun[u][r] = mn;
          lrun[u][r] *= fac;
#pragma unroll
          for (int cb = 0; cb < 8; ++cb) o[u][cb][r] *= fac;
        }
    }
#pragma unroll
    for (int u = 0; u < 2; ++u)
#pragma unroll
      for (int r = 0; r < 4; ++r) {
        float p0_ = __expf(s[u][0][r] - mrun[u][r]);
        float p1_ = __expf(s[u][1][r] - mrun[u][r]);
        float p2_ = __expf(s[u][2][r] - mrun[u][r]);
        lrun[u][r] += p0_ + p1_ + p2_;
        const int row = wv * 32 + u * 16 + g * 4 + r;
        unsigned char* prow = smP + row * 128;
        const int sw = (row & 7) << 4;
        *(unsigned short*)(prow + ((c * 2) ^ sw)) = f2bf(p0_);
        *(unsigned short*)(prow + ((32 + c * 2) ^ sw)) = f2bf(p1_);
        *(unsigned short*)(prow + ((64 + c * 2) ^ sw)) = f2bf(p2_);
      }

    // ---- O += P V ----
    s16x8 pa[2][2];
#pragma unroll
    for (int u = 0; u < 2; ++u)
#pragma unroll
      for (int ks = 0; ks < 2; ++ks)
        pa[u][ks] = *(const s16x8*)(smP + (wv * 32 + u * 16 + c) * 128 +
                                    ((ks * 64 + g * 16) ^ swzc));
#pragma unroll
    for (int ks = 0; ks < 2; ++ks)
#pragma unroll
      for (int cb = 0; cb < 8; ++cb) {
        s16x8 v = *(const s16x8*)(smV + (cb * 16 + c) * 128 + ((ks * 64 + g * 16) ^ swzc));
        o[0][cb] = __builtin_amdgcn_mfma_f32_16x16x32_bf16(pa[0][ks], v, o[0][cb], 0, 0, 0);
        o[1][cb] = __builtin_amdgcn_mfma_f32_16x16x32_bf16(pa[1][ks], v, o[1][cb], 0, 0, 0);
      }
  }

  // final per-row l reduce
#pragma unroll
  for (int u = 0; u < 2; ++u)
#pragma unroll
    for (int r = 0; r < 4; ++r) {
      lrun[u][r] += __shfl_xor(lrun[u][r], 1, 16);
      lrun[u][r] += __shfl_xor(lrun[u][r], 2, 16);
      lrun[u][r] += __shfl_xor(lrun[u][r], 4, 16);
      lrun[u][r] += __shfl_xor(lrun[u][r], 8, 16);
    }

  // coalesced Opart store via per-wave LDS transpose (own 4KB region of smP)
  const int l = tid & 63;
#pragma unroll
  for (int u = 0; u < 2; ++u) {
#pragma unroll
    for (int cb = 0; cb < 8; ++cb)
#pragma unroll
      for (int r = 0; r < 4; ++r) {
        const int row = g * 4 + r;
        *(unsigned short*)(smP + wv * 4096 + row * 256 +
                           (((cb * 16 + c) * 2) ^ ((row & 7) << 4))) = f2bf(o[u][cb][r]);
      }
#pragma unroll
    for (int j = 0; j < 4; ++j) {
      const int row = j * 4 + (l >> 4);
      const int off = (l & 15) * 16;
      s16x8 vd = *(const s16x8*)(smP + wv * 4096 + row * 256 + (off ^ ((row & 7) << 4)));
      const int p = qbaseW + u * 16 + row;
      *(s16x8*)((char*)Opart + (size_t)(pb + p) * 256 + off) = vd;
    }
  }
  if (c == 0) {
#pragma unroll
    for (int u = 0; u < 2; ++u)
#pragma unroll
      for (int r = 0; r < 4; ++r) {
        const int p = qbaseW + u * 16 + g * 4 + r;
        mlbuf[((size_t)pb + p) * 2 + 0] = mrun[u][r];
        mlbuf[((size_t)pb + p) * 2 + 1] = lrun[u][r];
      }
  }
}

// ---------------------------------------------------------------------------
// merge 4 split-K partials -> oatt[p][512] bf16 (p-major)
// ---------------------------------------------------------------------------
__global__ __launch_bounds__(256) void merge_kernel(
    const unsigned short* __restrict__ Opart, const float* __restrict__ mlbuf,
    unsigned short* __restrict__ oatt)
{
  int idx = (int)blockIdx.x * 256 + (int)threadIdx.x;  // 4*4608*32
  int d4 = idx & 31;
  int rest = idx >> 5;
  int p = rest % HW_N;
  int h = rest / HW_N;
  float m[4], lv[4];
#pragma unroll
  for (int s = 0; s < 4; ++s) {
    int ip = (s * 4 + h) * HW_N + p;
    m[s] = mlbuf[(size_t)ip * 2];
    lv[s] = mlbuf[(size_t)ip * 2 + 1];
  }
  float M = fmaxf(fmaxf(m[0], m[1]), fmaxf(m[2], m[3]));
  float a[4], den = 0.f;
#pragma unroll
  for (int s = 0; s < 4; ++s) { a[s] = __expf(m[s] - M); den += a[s] * lv[s]; }
  float rd = 1.f / den;
  f32x4 acc = {};
#pragma unroll
  for (int s = 0; s < 4; ++s) {
    int ip = (s * 4 + h) * HW_N + p;
    u16x4 ov = *(const u16x4*)(Opart + (size_t)ip * 128 + d4 * 4);
#pragma unroll
    for (int j = 0; j < 4; ++j) acc[j] = fmaf(a[s], bf2f(ov[j]), acc[j]);
  }
  u16x4 res;
#pragma unroll
  for (int j = 0; j < 4; ++j) res[j] = f2bf(acc[j] * rd);
  *(u16x4*)(oatt + (size_t)p * 512 + h * 128 + d4 * 4) = res;
}

// ---------------------------------------------------------------------------
// convout (MFMA): fm[p][256] bf16 = relu(bn(w_out @ oatt^T) + x); K=512
// grid (36, 4): C tile [64 oc][128 p]
// ---------------------------------------------------------------------------
__global__ __launch_bounds__(256) void convout_kernel(
    const unsigned short* __restrict__ oatt, const float* __restrict__ w,
    const float* __restrict__ gg, const float* __restrict__ bb,
    const float* __restrict__ mm, const float* __restrict__ vv,
    const float* __restrict__ x, unsigned short* __restrict__ fm)
{
  __shared__ __align__(16) unsigned char smA[8192];   // [64 oc][64 cc] bf16 swz
  __shared__ __align__(16) unsigned char smB[16384];  // [128 p][64 cc] bf16 swz
  const int tid = (int)threadIdx.x;
  const int wv = tid >> 6, g = (tid >> 4) & 3, c = tid & 15;
  const int p0 = (int)blockIdx.x * 128;
  const int o0 = (int)blockIdx.y * 64;
  const int swzc = (c & 7) << 4;
  const int aoc = tid >> 2, aq4 = tid & 3;
  const int brow = tid >> 3, bcol = (tid & 7) * 16;
  f32x4 acc[8];
#pragma unroll
  for (int cb = 0; cb < 8; ++cb) acc[cb] = {};

  for (int ch = 0; ch < 8; ++ch) {
    __syncthreads();
#pragma unroll
    for (int i = 0; i < 4; ++i)
      gload_lds16((const char*)oatt + (size_t)(p0 + i * 32 + brow) * 1024 + ch * 128 +
                      (bcol ^ ((brow & 7) << 4)),
                  smB + i * 4096 + wv * 1024);
    {
      const float* wp = w + (size_t)(o0 + aoc) * 512 + ch * 64 + aq4 * 16;
      f32x4 a0 = *(const f32x4*)(wp);
      f32x4 a1 = *(const f32x4*)(wp + 4);
      f32x4 a2 = *(const f32x4*)(wp + 8);
      f32x4 a3 = *(const f32x4*)(wp + 12);
      s16x8 w0, w1;
#pragma unroll
      for (int e = 0; e < 4; ++e) {
        w0[e] = (short)f2bf(a0[e]); w0[4 + e] = (short)f2bf(a1[e]);
        w1[e] = (short)f2bf(a2[e]); w1[4 + e] = (short)f2bf(a3[e]);
      }
      *(s16x8*)(smA + aoc * 128 + ((aq4 * 32) ^ ((aoc & 7) << 4))) = w0;
      *(s16x8*)(smA + aoc * 128 + ((aq4 * 32 + 16) ^ ((aoc & 7) << 4))) = w1;
    }
    __syncthreads();
#pragma unroll
    for (int kk = 0; kk < 2; ++kk) {
      s16x8 a = *(const s16x8*)(smA + (wv * 16 + c) * 128 + ((kk * 64 + g * 16) ^ swzc));
#pragma unroll
      for (int cb = 0; cb < 8; ++cb) {
        s16x8 b = *(const s16x8*)(smB + (cb * 16 + c) * 128 + ((kk * 64 + g * 16) ^ swzc));
        acc[cb] = __builtin_amdgcn_mfma_f32_16x16x32_bf16(a, b, acc[cb], 0, 0, 0);
      }
    }
  }

  __syncthreads();
  float inv[4], bia[4];
#pragma unroll
  for (int r = 0; r < 4; ++r) {
    int oc = o0 + wv * 16 + g * 4 + r;
    inv[r] = gg[oc] * rsqrtf(vv[oc] + EPS);
    bia[r] = bb[oc] - mm[oc] * inv[r];
  }
#pragma unroll
  for (int cb = 0; cb < 8; ++cb)
#pragma unroll
    for (int r = 0; r < 4; ++r) {
      int oc = o0 + wv * 16 + g * 4 + r;
      int p = p0 + cb * 16 + c;
      float v = fmaxf(acc[cb][r] * inv[r] + bia[r] + x[(size_t)oc * HW_N + p], 0.f);
      *(unsigned short*)(smB + (cb * 16 + c) * 128 +
                         (((wv * 16 + g * 4 + r) * 2) ^ swzc)) = f2bf(v);
    }
  __syncthreads();
#pragma unroll
  for (int i = 0; i < 4; ++i) {
    int row = i * 32 + brow;
    s16x8 vd = *(const s16x8*)(smB + row * 128 + (bcol ^ ((row & 7) << 4)));
    *(s16x8*)((char*)fm + (size_t)(p0 + row) * 512 + o0 * 2 + bcol) = vd;
  }
}

// ---------------------------------------------------------------------------
// convhead (MFMA): out[19][4608] = w_head @ fm^T + b_head; K=256. grid 36.
// ---------------------------------------------------------------------------
__global__ __launch_bounds__(256) void convhead_kernel(
    const unsigned short* __restrict__ fm, const float* __restrict__ w,
    const float* __restrict__ bh, float* __restrict__ outp)
{
  __shared__ __align__(16) unsigned char smA[4096];   // [32 oc][64 cc] bf16 swz
  __shared__ __align__(16) unsigned char smB[16384];  // [128 p][64 cc] bf16 swz
  const int tid = (int)threadIdx.x;
  const int wv = tid >> 6, g = (tid >> 4) & 3, c = tid & 15;
  const int p0 = (int)blockIdx.x * 128;
  const int swzc = (c & 7) << 4;
  const int aoc = tid >> 3, aq8 = tid & 7;
  const int brow = tid >> 3, bcol = (tid & 7) * 16;
  f32x4 acc[2][2];
#pragma unroll
  for (int u = 0; u < 2; ++u)
#pragma unroll
    for (int cbi = 0; cbi < 2; ++cbi) acc[u][cbi] = {};

  for (int ch = 0; ch < 4; ++ch) {
    __syncthreads();
#pragma unroll
    for (int i = 0; i < 4; ++i)
      gload_lds16((const char*)fm + (size_t)(p0 + i * 32 + brow) * 512 + ch * 128 +
                      (bcol ^ ((brow & 7) << 4)),
                  smB + i * 4096 + wv * 1024);
    {
      s16x8 w0 = {};
      if (aoc < 19) {
        const float* wp = w + (size_t)aoc * 256 + ch * 64 + aq8 * 8;
        f32x4 a0 = *(const f32x4*)(wp);
        f32x4 a1 = *(const f32x4*)(wp + 4);
#pragma unroll
        for (int e = 0; e < 4; ++e) {
          w0[e] = (short)f2bf(a0[e]);
          w0[4 + e] = (short)f2bf(a1[e]);
        }
      }
      *(s16x8*)(smA + aoc * 128 + ((aq8 * 16) ^ ((aoc & 7) << 4))) = w0;
    }
    __syncthreads();
#pragma unroll
    for (int kk = 0; kk < 2; ++kk) {
      s16x8 a0 = *(const s16x8*)(smA + c * 128 + ((kk * 64 + g * 16) ^ swzc));
      s16x8 a1 = *(const s16x8*)(smA + (16 + c) * 128 + ((kk * 64 + g * 16) ^ swzc));
#pragma unroll
      for (int cbi = 0; cbi < 2; ++cbi) {
        int cb = wv * 2 + cbi;
        s16x8 b = *(const s16x8*)(smB + (cb * 16 + c) * 128 + ((kk * 64 + g * 16) ^ swzc));
        acc[0][cbi] = __builtin_amdgcn_mfma_f32_16x16x32_bf16(a0, b, acc[0][cbi], 0, 0, 0);
        acc[1][cbi] = __builtin_amdgcn_mfma_f32_16x16x32_bf16(a1, b, acc[1][cbi], 0, 0, 0);
      }
    }
  }
#pragma unroll
  for (int u = 0; u < 2; ++u)
#pragma unroll
    for (int cbi = 0; cbi < 2; ++cbi)
#pragma unroll
      for (int r = 0; r < 4; ++r) {
        int oc = u * 16 + g * 4 + r;
        if (oc < 19) {
          int p = p0 + (wv * 2 + cbi) * 16 + c;
          outp[(size_t)oc * HW_N + p] = acc[u][cbi][r] + bh[oc];
        }
      }
}

// ---------------------------------------------------------------------------
extern "C" void kernel_launch(void* const* d_in, const int* in_sizes, int n_in,
                              void* d_out, int out_size, void* d_ws, size_t ws_size,
                              hipStream_t stream)
{
  const float* x     = (const float*)d_in[0];
  const float* w_in  = (const float*)d_in[1];
  const float* bn1_g = (const float*)d_in[2];
  const float* bn1_b = (const float*)d_in[3];
  const float* bn1_m = (const float*)d_in[4];
  const float* bn1_v = (const float*)d_in[5];
  const float* w_qkv = (const float*)d_in[6];
  const float* rel_h = (const float*)d_in[7];
  const float* rel_w = (const float*)d_in[8];
  const float* w_out = (const float*)d_in[9];
  const float* bn2_g = (const float*)d_in[10];
  const float* bn2_b = (const float*)d_in[11];
  const float* bn2_m = (const float*)d_in[12];
  const float* bn2_v = (const float*)d_in[13];
  const float* w_hd  = (const float*)d_in[14];
  const float* b_hd  = (const float*)d_in[15];

  char* ws = (char*)d_ws;
  float*          h1    = (float*)(ws + 0);                   // 1,179,648 B
  float*          mlb   = (float*)(ws + 0);                   // 589,824 B (h1 dead)
  unsigned short* qb    = (unsigned short*)(ws + 1179648);    // 4,718,592 B
  unsigned short* kb    = (unsigned short*)(ws + 5898240);    // 4,718,592 B
  unsigned short* vb    = (unsigned short*)(ws + 10616832);   // 4,718,592 B
  float*          RW    = (float*)(ws + 15335424);            // 7,077,888 B
  float*          RH    = (float*)(ws + 22413312);            // 3,538,944 B
  unsigned short* Opart = (unsigned short*)(ws + 25952256);   // 18,874,368 B
  unsigned short* oatt  = (unsigned short*)(ws + 44826624);   // 4,718,592 B (bf16)
  unsigned short* fm    = (unsigned short*)(ws + 49545216);   // 2,359,296 B (bf16)

  conv1_kernel<<<72, 256, 0, stream>>>(x, w_in, bn1_g, bn1_b, bn1_m, bn1_v, h1);
  convqkv_kernel<<<dim3(72, 24), 256, 0, stream>>>(h1, w_qkv, qb, kb, vb);
  relpre_mfma<<<dim3(144, 4), 256, 0, stream>>>(qb, rel_h, rel_w, RW, RH);
  attn_kernel<<<dim3(36, 4, 4), 256, 0, stream>>>(qb, kb, vb, RW, RH, Opart, mlb);
  merge_kernel<<<2304, 256, 0, stream>>>(Opart, mlb, oatt);
  convout_kernel<<<dim3(36, 4), 256, 0, stream>>>(oatt, w_out, bn2_g, bn2_b, bn2_m,
                                                  bn2_v, x, fm);
  convhead_kernel<<<36, 256, 0, stream>>>(fm, w_hd, b_hd, (float*)d_out);
}